// Round 15
// baseline (102.256 us; speedup 1.0000x reference)
//
#include <hip/hip_runtime.h>

#define BATCH  65536
#define NIN    9
#define NHID   100
#define TSTEPS 25
#define CHUNK  5
#define EPS    5e-5f

typedef float v2f __attribute__((ext_vector_type(2)));

// Wave-uniform neuron mapping (block = 64 batch elems, wave wq owns neurons
// [25wq,25wq+25)); weights via SGPR scalar loads (r10 structure, 43.6us).
// ROUND-15: the m-chain runs in f32 (7 inst/step vs f64's ~26 cyc/step),
// tracking min|m-1| per neuron. If any lane's margin < EPS (~2% of
// neuron-waves), a wave-uniform fallback replays the f32 chain (bit-exact
// replay: explicit fmaf, same inputs) alongside the EXACT f64 chain of
// rounds 2-14 and patches acc[t] by ±w where decisions differ. Result:
// spike decisions identical to the f64 arbiter-tracking chain; acc sums
// reorder-class only (passed bit-identically in r6/r13).
__global__ __launch_bounds__(256) void snn_kernel(
    const float* __restrict__ x,  const float* __restrict__ W1,
    const float* __restrict__ b1, const float* __restrict__ W2,
    const float* __restrict__ b2, float* __restrict__ out)
{
    __shared__ float sx[64 * NIN];              // 2.25 KB staged x rows
    __shared__ v2f   sacc[2][4][CHUNK][64];     // 20.5 KB double-buffered reduce

    const int tid  = threadIdx.x;
    const int lane = tid & 63;
    const int wq   = __builtin_amdgcn_readfirstlane(tid >> 6);
    const int b0   = blockIdx.x * 64;

    for (int i = tid; i < 64 * NIN; i += 256) sx[i] = x[(size_t)b0 * NIN + i];
    __syncthreads();

    // per-lane x row, f32 (exact input values)
    float xv[NIN];
#pragma unroll
    for (int i = 0; i < NIN; ++i) xv[i] = sx[lane * NIN + i];

    // per-step fc2 partial sums (d*w is exact, so fma/mul+add codegen-safe)
    v2f acc[TSTEPS];
#pragma unroll
    for (int t = 0; t < TSTEPS; ++t) acc[t] = (v2f){0.f, 0.f};

    const int h0 = wq * 25;
#pragma unroll 1
    for (int j = 0; j < 25; ++j) {
        const int h = h0 + j;                  // wave-uniform -> s_load weights
        // f32 input current (decides spikes only when margin > EPS)
        float c32 = 0.f;
#pragma unroll
        for (int i = 0; i < NIN; ++i) c32 = fmaf(W1[h * NIN + i], xv[i], c32);
        c32 += b1[h];
        const float c1_32 = c32 - 1.0f;
        const float w0 = W2[h], w1 = W2[NHID + h];
        const v2f   w  = (v2f){w0, w1};

        float m = 0.f, ming = 1e30f;
        bool  s = false;                       // spike(t-1) == reset(t)
#pragma unroll
        for (int t = 0; t < TSTEPS; ++t) {
            float cs = s ? c1_32 : c32;
            m = fmaf(0.95f, m, cs);            // f32 leaky integrate + reset
            float g = m - 1.0f;
            s = (g > 0.0f);                    // f32 spike decision
            ming = fminf(ming, fabsf(g));      // margin tracking (1 v_min)
            float d = s ? 1.f : 0.f;
            acc[t] += (v2f){d, d} * w;
        }

        // rare exact-f64 fallback: any lane within EPS of the threshold
        if (__any(ming < EPS)) {
            double c64 = 0.0;
#pragma unroll
            for (int i = 0; i < NIN; ++i)
                c64 += (double)W1[h * NIN + i] * (double)xv[i];  // r2-r14 order
            c64 += (double)b1[h];
            const double c1_64 = c64 - 1.0;

            double md = 0.0;  bool sd = false;   // exact f64 chain (bit-identical)
            float  mr = 0.f;  bool sr = false;   // f32 replay (bit-identical to above)
#pragma unroll
            for (int t = 0; t < TSTEPS; ++t) {
                float csr = sr ? c1_32 : c32;
                mr = fmaf(0.95f, mr, csr);
                sr = ((mr - 1.0f) > 0.0f);
                md = 0.95 * md + (sd ? c1_64 : c64);
                sd = (md > 1.0);
                if (sr != sd) {                  // patch acc to f64 decision
                    float sg = sd ? 1.f : -1.f;
                    acc[t] += (v2f){sg, sg} * w;
                }
            }
        }
    }

    // chunked cross-wave reduce + mem2 (wave 0), double-buffered LDS.
    // All acc indices compile-time constants (round-9 lesson).
    double m20 = 0.0, m21 = 0.0;
    double bb0 = (double)b2[0], bb1 = (double)b2[1];

#pragma unroll
    for (int k = 0; k < TSTEPS / CHUNK; ++k) {
#pragma unroll
        for (int u = 0; u < CHUNK; ++u)
            sacc[k & 1][wq][u][lane] = acc[k * CHUNK + u];
        __syncthreads();
        // wave0 reads buf[k&1] before the NEXT barrier; other waves can't
        // overwrite buf[k&1] until chunk k+2's writes, behind that barrier.
        if (wq == 0) {
#pragma unroll
            for (int u = 0; u < CHUNK; ++u) {
                const int t = k * CHUNK + u;
                v2f q0 = sacc[k & 1][0][u][lane];
                v2f q1 = sacc[k & 1][1][u][lane];
                v2f q2 = sacc[k & 1][2][u][lane];
                v2f q3 = sacc[k & 1][3][u][lane];
                v2f sum = (q0 + q1) + (q2 + q3);   // butterfly bracketing
                double r0 = (m20 > 1.0) ? 1.0 : 0.0;
                double r1 = (m21 > 1.0) ? 1.0 : 0.0;
                m20 = 0.95 * m20 + ((double)sum[0] + bb0) - r0;
                m21 = 0.95 * m21 + ((double)sum[1] + bb1) - r1;
                *(float2*)(out + ((size_t)t * BATCH + b0 + lane) * 2) =
                    make_float2((float)m20, (float)m21);
            }
        }
    }
}

extern "C" void kernel_launch(void* const* d_in, const int* in_sizes, int n_in,
                              void* d_out, int out_size, void* d_ws, size_t ws_size,
                              hipStream_t stream) {
    const float* x  = (const float*)d_in[0];
    const float* W1 = (const float*)d_in[1];
    const float* b1 = (const float*)d_in[2];
    const float* W2 = (const float*)d_in[3];
    const float* b2 = (const float*)d_in[4];
    float* out = (float*)d_out;

    dim3 grid(BATCH / 64), block(256);
    hipLaunchKernelGGL(snn_kernel, grid, block, 0, stream, x, W1, b1, W2, b2, out);
}